// Round 14
// baseline (216.020 us; speedup 1.0000x reference)
//
#include <hip/hip_runtime.h>
#include <hip/hip_bf16.h>

typedef __attribute__((ext_vector_type(8))) short bf16x8;
typedef __attribute__((ext_vector_type(4))) float f32x4;

#define B     4
#define CIN   128
#define COUT  256
#define H     256
#define W     256
#define HW    (H * W)
#define ROWS  16         // rows per block
#define PXW   64         // px strip per block
#define CHUNK 4          // rows per pipeline chunk
#define NCH   (ROWS / CHUNK)

__device__ __forceinline__ unsigned short f2bf(float f) {
  unsigned int u = __builtin_bit_cast(unsigned int, f);
  u += 0x7fff + ((u >> 16) & 1);
  return (unsigned short)(u >> 16);
}

__global__ void cvt_wpw(const float* __restrict__ w, unsigned short* __restrict__ o) {
  int i = blockIdx.x * 256 + threadIdx.x;
  if (i < COUT * CIN) o[i] = f2bf(w[i]);
}

// 16-px row fragment + 1-px halos (R9-proven math, correctness-wise)
struct R16 { f32x4 v0, v1, v2, v3; float L, R; };

__device__ __forceinline__ float rg(const R16& r, int j) {
  if (j < 0)  return r.L;
  if (j < 4)  return r.v0[j & 3];
  if (j < 8)  return r.v1[j & 3];
  if (j < 12) return r.v2[j & 3];
  if (j < 16) return r.v3[j & 3];
  return r.R;
}

__device__ __forceinline__ R16 lrow(const float* xr, int px0, bool pL, bool pR) {
  R16 r;
  r.v0 = *(const f32x4*)(xr + px0);
  r.v1 = *(const f32x4*)(xr + px0 + 4);
  r.v2 = *(const f32x4*)(xr + px0 + 8);
  r.v3 = *(const f32x4*)(xr + px0 + 12);
  r.L = pL ? xr[px0 - 1] : 0.f;
  r.R = pR ? xr[px0 + 16] : 0.f;
  return r;
}

__device__ __forceinline__ R16 zrow() {
  R16 r; r.L = r.R = 0.f;
  r.v0 = r.v1 = r.v2 = r.v3 = (f32x4){0.f,0.f,0.f,0.f};
  return r;
}

// Chunk-buffer layout: La = rr*16384 + pxl*256 + ci*2 (bytes), 4x64x128 bf16=64KB.
// swz XORs granule bits 4-6 with (pxl&7)^(pxl>>3):
//   producer u16 writes -> 32 banks x 2 lanes (free)
//   consumer b128 reads -> granule-balanced (b128 floor)
__device__ __forceinline__ unsigned swz(unsigned La) {
  unsigned g = ((La >> 8) & 7) ^ ((La >> 11) & 7);
  return La ^ (g << 4);
}

// ---------------------------------------------------------------------------
// R14: producer/consumer WAVE-SPECIALIZED fused dw3x3 + pw GEMM.
// R12 counters: FETCH 80MB (x L3-resident), WRITE 265MB, nothing busy ->
// phase lockstep starves the store pipe half the time. Fix: within a block,
// waves 0-7 produce dw rows into LDS chunk c+1 WHILE waves 8-15 GEMM+store
// chunk c. Stores flow continuously -> store-BW-limited span (~42us) + fill.
// Block = 16 rows x 64 px x 128 ci; grid 256 = 1 block/CU, ONE generation.
// LDS: 2 chunk buffers x 64 KB (4 rows each). 4 barriers/block.
// Producer thread = 1 ci x 16 px, windows CHUNK-LOCAL (re-read boundary rows
// from L1/L2 -> no persistent window regs, no spill; R11 lesson).
// Consumer wave = 32 co x 64 px per row; Af reloaded per chunk (L2-hot).
// ---------------------------------------------------------------------------
__global__ __launch_bounds__(1024, 4) void fused_kernel(
    const float* __restrict__ x, const float* __restrict__ wdw,
    const unsigned short* __restrict__ wb, float* __restrict__ out)
{
  int bid = blockIdx.x;
  int xcd = bid & 7;
  int k   = bid >> 3;            // 0..31
  int hc  = xcd * 2 + (k & 1);   // 0..15: each XCD owns 2 consecutive h-chunks
  int s   = (k >> 1) & 3;        // 4 strips of 64 px
  int b   = k >> 3;              // 0..3
  int hBase = hc * ROWS;         // 0..240

  int t = threadIdx.x;
  bool producer = t < 512;       // waves 0-7 produce, 8-15 consume

  __shared__ __align__(16) char yb[2][CHUNK * PXW * 256];   // 2 x 64 KB

  // ---- producer persistent state (small: ids + weights + base ptr) ----
  int ci = 0, pxg = 0, gpx0 = 0; bool pL = false, pR = false;
  float wr[9];
  const float* xc = nullptr;
  if (producer) {
    ci   = t >> 2;               // 0..127
    pxg  = t & 3;                // 0..3, 16 px each
    gpx0 = s * PXW + pxg * 16;
    pL = gpx0 > 0; pR = gpx0 + 16 < W;
#pragma unroll
    for (int q = 0; q < 9; ++q) wr[q] = wdw[ci * 9 + q];
    xc = x + ((size_t)b * CIN + ci) * HW;
  }

  // ---- consumer persistent ids ----
  int l15 = 0, lg = 0, coBase = 0;
  if (!producer) {
    int ct = t - 512;
    int cw = ct >> 6;            // 0..7
    int l  = ct & 63;
    l15 = l & 15; lg = l >> 4;
    coBase = cw * 32;
  }

  auto consume = [&](int cc) {
    const char* buf = &yb[cc & 1][0];
    bf16x8 Af[2][4];             // reload per chunk: wb is L2-hot (64 KB)
#pragma unroll
    for (int m = 0; m < 2; ++m)
#pragma unroll
      for (int kk = 0; kk < 4; ++kk)
        Af[m][kk] = *(const bf16x8*)(wb + (coBase + m * 16 + l15) * CIN + kk * 32 + lg * 8);

    float* ob = out + (size_t)b * COUT * HW + s * PXW;
#pragma unroll
    for (int rr = 0; rr < CHUNK; ++rr) {
      int h = hBase + cc * CHUNK + rr;
      f32x4 acc[2][4];
#pragma unroll
      for (int m = 0; m < 2; ++m)
#pragma unroll
        for (int n = 0; n < 4; ++n) acc[m][n] = (f32x4){0.f,0.f,0.f,0.f};

#pragma unroll
      for (int n = 0; n < 4; ++n) {
        bf16x8 Yf[4];
#pragma unroll
        for (int kk = 0; kk < 4; ++kk) {
          unsigned La = (unsigned)rr * 16384u + (unsigned)(n * 16 + l15) * 256u
                      + (unsigned)(kk * 32 + lg * 8) * 2u;
          Yf[kk] = *(const bf16x8*)(buf + swz(La));
        }
#pragma unroll
        for (int m = 0; m < 2; ++m)
#pragma unroll
          for (int kk = 0; kk < 4; ++kk)
            acc[m][n] = __builtin_amdgcn_mfma_f32_16x16x32_bf16(Af[m][kk], Yf[kk], acc[m][n], 0, 0, 0);
      }

      float* orow = ob + (size_t)h * W;
#pragma unroll
      for (int m = 0; m < 2; ++m)
#pragma unroll
        for (int n = 0; n < 4; ++n)
#pragma unroll
          for (int q = 0; q < 4; ++q)
            orow[(size_t)(coBase + m * 16 + lg * 4 + q) * HW + n * 16 + l15] = acc[m][n][q];
    }
  };

  for (int c = 0; c < NCH; ++c) {
    if (producer) {
      char* buf = &yb[c & 1][0];
      int r0 = hBase + c * CHUNK;
      // chunk-local rolling window (boundary rows re-hit L1/L2)
      R16 A  = (r0 > 0) ? lrow(xc + (size_t)(r0 - 1) * W, gpx0, pL, pR) : zrow();
      R16 Bv = lrow(xc + (size_t)r0 * W, gpx0, pL, pR);
      R16 C  = lrow(xc + (size_t)(r0 + 1) * W, gpx0, pL, pR);   // r0+1 <= 253
#pragma unroll
      for (int rr = 0; rr < CHUNK; ++rr) {
        R16 D;
        if (rr < CHUNK - 1) {
          int hh = r0 + rr + 2;
          bool ok = hh < H;          // block-uniform; false only at bottom edge
          D = ok ? lrow(xc + (size_t)hh * W, gpx0, pL, pR) : zrow();
        }
#pragma unroll
        for (int j = 0; j < 16; ++j) {
          float a =
            rg(A, j-1)*wr[0] + rg(A, j)*wr[1] + rg(A, j+1)*wr[2] +
            rg(Bv,j-1)*wr[3] + rg(Bv,j)*wr[4] + rg(Bv,j+1)*wr[5] +
            rg(C, j-1)*wr[6] + rg(C, j)*wr[7] + rg(C, j+1)*wr[8];
          unsigned La = (unsigned)rr * 16384u + (unsigned)(pxg * 16 + j) * 256u
                      + (unsigned)ci * 2u;
          *(unsigned short*)(buf + swz(La)) = f2bf(a);
        }
        if (rr < CHUNK - 1) { A = Bv; Bv = C; C = D; }
      }
    } else if (c >= 1) {
      consume(c - 1);
    }
    __syncthreads();
  }
  if (!producer) consume(NCH - 1);
}

extern "C" void kernel_launch(void* const* d_in, const int* in_sizes, int n_in,
                              void* d_out, int out_size, void* d_ws, size_t ws_size,
                              hipStream_t stream) {
  const float* x   = (const float*)d_in[0];
  const float* wdw = (const float*)d_in[1];
  const float* wpw = (const float*)d_in[2];
  float* out = (float*)d_out;

  unsigned short* wbb = (unsigned short*)d_ws;   // 64 KB bf16 pw weights

  cvt_wpw<<<(COUT * CIN + 255) / 256, 256, 0, stream>>>(wpw, wbb);
  fused_kernel<<<B * (H / ROWS) * (W / PXW), 1024, 0, stream>>>(x, wdw, wbb, out);
}

// Round 15
// 155.323 us; speedup vs baseline: 1.3908x; 1.3908x over previous
//
#include <hip/hip_runtime.h>
#include <hip/hip_bf16.h>

typedef __attribute__((ext_vector_type(8))) short bf16x8;
typedef __attribute__((ext_vector_type(4))) float f32x4;

#define B    4
#define CIN  128
#define COUT 256
#define H    256
#define W    256
#define HW   (H * W)
#define ROWS 8           // rows per block (4 pairs)
#define PXW  64          // px strip per block

__device__ __forceinline__ unsigned short f2bf(float f) {
  unsigned int u = __builtin_bit_cast(unsigned int, f);
  u += 0x7fff + ((u >> 16) & 1);
  return (unsigned short)(u >> 16);
}

__global__ void cvt_wpw(const float* __restrict__ w, unsigned short* __restrict__ o) {
  int i = blockIdx.x * 256 + threadIdx.x;
  if (i < COUT * CIN) o[i] = f2bf(w[i]);
}

struct Row { float L; f32x4 a; f32x4 b; float R; };

__device__ __forceinline__ float rget(const Row& r, int j) {
  return (j < 0) ? r.L : (j < 4) ? r.a[j & 3] : (j < 8) ? r.b[j & 3] : r.R;
}

__device__ __forceinline__ Row load_row(const float* xr, int px0, bool pL, bool pR) {
  Row r;
  r.a = *(const f32x4*)(xr + px0);
  r.b = *(const f32x4*)(xr + px0 + 4);
  r.L = pL ? xr[px0 - 1] : 0.f;
  r.R = pR ? xr[px0 + 8] : 0.f;
  return r;
}

__device__ __forceinline__ Row zero_row() {
  Row r; r.L = r.R = 0.f;
  r.a = (f32x4){0.f,0.f,0.f,0.f};
  r.b = (f32x4){0.f,0.f,0.f,0.f};
  return r;
}

// Pair-buffer layout: byte = buf*32768 + rr*16384 + pxl*256 + ci*2.
// swz (bits 8-10 ^= bits 11-13 into granule bits 4-6) exactly as R8/R12:
// dw u16 writes 2 lanes/bank (free), GEMM b128 reads granule-balanced.
__device__ __forceinline__ unsigned swz(unsigned La) {
  unsigned g = ((La >> 8) & 7) ^ ((La >> 11) & 7);
  return La ^ (g << 4);
}

// ---------------------------------------------------------------------------
// R15: in-wave row-pair pipeline. R12 ledger: dw 28us/gen (stores idle) +
// GEMM 21us/gen (store-drain). Merge them: per step, stores of pair k-1
// drain under dw of pair k. Raw s_barrier + lgkmcnt(0) ONLY inside the loop
// (no vmcnt drain -> stores stay in flight across barriers).
// Block = 8 rows x 64 px x 128 ci, 1024 thr, 64 KB LDS (2x32KB pair dbuf).
// dw: thread = 1 ci x 8 px, explicit 6-Row rotation (A,B,C,D + C2,D2).
// GEMM (R13-verified swapped operands): wave = 16 co; D[px][co] -> f32x4
// stores. Grid 512 (2 gens), 1 block/CU, 16 waves.
// ---------------------------------------------------------------------------
__global__ __launch_bounds__(1024, 4) void fused_kernel(
    const float* __restrict__ x, const float* __restrict__ wdw,
    const unsigned short* __restrict__ wb, float* __restrict__ out)
{
  int bid = blockIdx.x;
  int xcd = bid & 7;
  int k   = bid >> 3;          // 0..63
  int hcl = k & 3;
  int s   = (k >> 2) & 3;      // 4 strips of 64 px
  int b   = k >> 4;            // 0..3
  int hc  = xcd * 4 + hcl;     // 0..31
  int hBase = hc * ROWS;       // 0..248

  int t = threadIdx.x;
  int ci  = t >> 3;            // 0..127
  int pxg = t & 7;             // 0..7, 8 px each
  int px0 = s * PXW + pxg * 8;
  bool pL = px0 > 0, pR = px0 + 8 < W;

  __shared__ __align__(16) char yb[2 * 32768];   // 64 KB: 2 pair-buffers

  float wr[9];
#pragma unroll
  for (int q = 0; q < 9; ++q) wr[q] = wdw[ci * 9 + q];

  const float* xc = x + ((size_t)b * CIN + ci) * HW;

  // GEMM ids (R13-verified swapped mapping)
  int wave = t >> 6, l = t & 63;
  int l15 = l & 15, lg = l >> 4;
  int coBase = wave * 16;      // 16 waves x 16 co = 256

  bf16x8 Wf[4];
#pragma unroll
  for (int kk = 0; kk < 4; ++kk)
    Wf[kk] = *(const bf16x8*)(wb + (coBase + l15) * CIN + kk * 32 + lg * 8);

  // dw of one row (rows indexed by window Ra=h-1, Rb=h, Rc=h+1) into buf/rr
  auto dw_row = [&](char* buf, int rr, const Row& Ra, const Row& Rb, const Row& Rc) {
#pragma unroll
    for (int j = 0; j < 8; ++j) {
      float a =
        rget(Ra, j-1)*wr[0] + rget(Ra, j)*wr[1] + rget(Ra, j+1)*wr[2] +
        rget(Rb, j-1)*wr[3] + rget(Rb, j)*wr[4] + rget(Rb, j+1)*wr[5] +
        rget(Rc, j-1)*wr[6] + rget(Rc, j)*wr[7] + rget(Rc, j+1)*wr[8];
      unsigned La = (unsigned)rr * 16384u + (unsigned)(pxg * 8 + j) * 256u + (unsigned)ci * 2u;
      *(unsigned short*)(buf + swz(La)) = f2bf(a);
    }
  };

  // GEMM + stores of one pair p from buf
  auto gemm_pair = [&](const char* buf, int p) {
    float* ob = out + (size_t)b * COUT * HW + s * PXW;
#pragma unroll
    for (int rr = 0; rr < 2; ++rr) {
      int h = hBase + p * 2 + rr;
      float* orow = ob + (size_t)h * W + (size_t)(coBase + l15) * HW;
#pragma unroll
      for (int m = 0; m < 4; ++m) {
        bf16x8 Yf[4];
#pragma unroll
        for (int kk = 0; kk < 4; ++kk) {
          unsigned La = (unsigned)rr * 16384u + (unsigned)(m * 16 + l15) * 256u
                      + (unsigned)(kk * 32 + lg * 8) * 2u;
          Yf[kk] = *(const bf16x8*)(buf + swz(La));
        }
        f32x4 acc = (f32x4){0.f,0.f,0.f,0.f};
#pragma unroll
        for (int kk = 0; kk < 4; ++kk)
          acc = __builtin_amdgcn_mfma_f32_16x16x32_bf16(Yf[kk], Wf[kk], acc, 0, 0, 0);
        *(f32x4*)(orow + m * 16 + lg * 4) = acc;   // D: px=m*16+lg*4+q, co=coBase+l15
      }
    }
  };

  // ---- prologue: window rows hBase-1..hBase+2, lookahead +3,+4 ----
  Row A  = (hBase > 0) ? load_row(xc + (size_t)(hBase - 1) * W, px0, pL, pR) : zero_row();
  Row Bv = load_row(xc + (size_t)(hBase + 0) * W, px0, pL, pR);
  Row C  = load_row(xc + (size_t)(hBase + 1) * W, px0, pL, pR);   // <= 249
  Row D  = load_row(xc + (size_t)(hBase + 2) * W, px0, pL, pR);   // <= 250
  Row C2 = load_row(xc + (size_t)(hBase + 3) * W, px0, pL, pR);   // <= 251
  Row D2 = load_row(xc + (size_t)(hBase + 4) * W, px0, pL, pR);   // <= 252

  dw_row(yb, 0, A, Bv, C);
  dw_row(yb, 1, Bv, C, D);
  asm volatile("s_waitcnt lgkmcnt(0)" ::: "memory");
  __builtin_amdgcn_s_barrier();

  // ---- steps k=1..3: rotate, prefetch, GEMM(k-1)+stores, dw(k), barrier ----
#pragma unroll
  for (int kp = 1; kp < 4; ++kp) {
    A = C; Bv = D; C = C2; D = D2;
    if (kp < 3) {
      int hh = hBase + 2 * kp + 3;
      bool ok = (hh + 1) < H;            // block-uniform; false only at bottom
      C2 = load_row(xc + (size_t)hh * W, px0, pL, pR);       // hh <= 253 valid
      D2 = ok ? load_row(xc + (size_t)(hh + 1) * W, px0, pL, pR) : zero_row();
    }
    char* wbuf = yb + (kp & 1) * 32768;
    const char* rbuf = yb + ((kp - 1) & 1) * 32768;

    gemm_pair(rbuf, kp - 1);             // stores fire-and-forget
    dw_row(wbuf, 0, A, Bv, C);           // pair kp rows
    dw_row(wbuf, 1, Bv, C, D);
    asm volatile("s_waitcnt lgkmcnt(0)" ::: "memory");
    __builtin_amdgcn_s_barrier();        // NO vmcnt: stores stay in flight
  }

  gemm_pair(yb + 32768, 3);              // final pair (buf1)
}

extern "C" void kernel_launch(void* const* d_in, const int* in_sizes, int n_in,
                              void* d_out, int out_size, void* d_ws, size_t ws_size,
                              hipStream_t stream) {
  const float* x   = (const float*)d_in[0];
  const float* wdw = (const float*)d_in[1];
  const float* wpw = (const float*)d_in[2];
  float* out = (float*)d_out;

  unsigned short* wbb = (unsigned short*)d_ws;   // 64 KB bf16 pw weights

  cvt_wpw<<<(COUT * CIN + 255) / 256, 256, 0, stream>>>(wpw, wbb);
  fused_kernel<<<B * (H / ROWS) * (W / PXW), 1024, 0, stream>>>(x, wdw, wbb, out);
}